// Round 1
// baseline (539.886 us; speedup 1.0000x reference)
//
#include <hip/hip_runtime.h>
#include <math.h>

#define CHN 96      // input/output channels
#define EC 192      // expanded channels
#define SS 16       // ssm state dim
#define WPIX 128    // sequence length (W axis)
#define XPAD 100    // padded LDS row stride for x (odd quad stride -> conflict-free)
#define TILE 16     // pixels per tile
#define NTILES (WPIX / TILE)
#define NT 192      // threads per block (= EC, 3 waves)

__global__ __launch_bounds__(NT)
void mamba_fused(const float* __restrict__ in,
                 const float* __restrict__ gamma,
                 const float* __restrict__ beta,
                 const float* __restrict__ We,
                 const float* __restrict__ Wg,
                 const float* __restrict__ Ap,
                 const float* __restrict__ Bp,
                 const float* __restrict__ Cp,
                 const float* __restrict__ Dp,
                 const float* __restrict__ Wo,
                 float* __restrict__ out) {
    __shared__ float xs[WPIX][XPAD];   // layernormed input row, 51.2 KB
    __shared__ float gs[TILE][EC];     // gated tile, 12.3 KB

    const int t = threadIdx.x;
    const int row = blockIdx.x;                      // (b*128 + h)
    const float* inrow = in + (size_t)row * WPIX * CHN;

    // ---- load row [128][96] into LDS (float4, coalesced) ----
    for (int q = t; q < WPIX * CHN / 4; q += NT) {
        const int w  = q / (CHN / 4);
        const int c4 = q % (CHN / 4);
        float4 v = *(const float4*)(inrow + (size_t)q * 4);
        *(float4*)&xs[w][c4 * 4] = v;
    }
    __syncthreads();

    // ---- LayerNorm in-place: one pixel per thread (threads 0..127) ----
    if (t < WPIX) {
        float sum = 0.f, sq = 0.f;
        #pragma unroll
        for (int c4 = 0; c4 < CHN / 4; ++c4) {
            float4 v = *(const float4*)&xs[t][c4 * 4];
            sum += v.x + v.y + v.z + v.w;
            sq  += v.x * v.x + v.y * v.y + v.z * v.z + v.w * v.w;
        }
        const float mean = sum * (1.f / CHN);
        const float var  = sq * (1.f / CHN) - mean * mean;
        const float rstd = rsqrtf(var + 1e-3f);
        #pragma unroll
        for (int c4 = 0; c4 < CHN / 4; ++c4) {
            float4 v = *(const float4*)&xs[t][c4 * 4];
            v.x = (v.x - mean) * rstd * gamma[c4 * 4 + 0] + beta[c4 * 4 + 0];
            v.y = (v.y - mean) * rstd * gamma[c4 * 4 + 1] + beta[c4 * 4 + 1];
            v.z = (v.z - mean) * rstd * gamma[c4 * 4 + 2] + beta[c4 * 4 + 2];
            v.w = (v.w - mean) * rstd * gamma[c4 * 4 + 3] + beta[c4 * 4 + 3];
            *(float4*)&xs[t][c4 * 4] = v;
        }
    }
    __syncthreads();

    // ---- persistent per-channel scan parameters (thread t owns channel e=t) ----
    const int e = t;
    float Ar[SS], Br[SS], Cr[SS], st[SS];
    const float d = Dp[e];
    #pragma unroll
    for (int s4 = 0; s4 < SS / 4; ++s4) {
        float4 a = *(const float4*)&Ap[e * SS + s4 * 4];
        float4 b = *(const float4*)&Bp[e * SS + s4 * 4];
        float4 c = *(const float4*)&Cp[e * SS + s4 * 4];
        Ar[s4*4+0]=a.x; Ar[s4*4+1]=a.y; Ar[s4*4+2]=a.z; Ar[s4*4+3]=a.w;
        Br[s4*4+0]=b.x; Br[s4*4+1]=b.y; Br[s4*4+2]=b.z; Br[s4*4+3]=b.w;
        Cr[s4*4+0]=c.x; Cr[s4*4+1]=c.y; Cr[s4*4+2]=c.z; Cr[s4*4+3]=c.w;
    }
    #pragma unroll
    for (int s = 0; s < SS; ++s) st[s] = 0.f;

    const int co  = t % CHN;   // output-channel for phase O
    const int wgr = t / CHN;   // pixel half (0/1) for phase O

    for (int tile = 0; tile < NTILES; ++tile) {
        const int w0 = tile * TILE;

        // ---- expand + gate matmuls: acc over c, 16 pixels per weight load ----
        float accp[TILE], accg[TILE];
        #pragma unroll
        for (int w = 0; w < TILE; ++w) { accp[w] = 0.f; accg[w] = 0.f; }

        for (int c4 = 0; c4 < CHN / 4; ++c4) {
            const int c = c4 * 4;
            const float we0 = We[(c + 0) * EC + e];
            const float we1 = We[(c + 1) * EC + e];
            const float we2 = We[(c + 2) * EC + e];
            const float we3 = We[(c + 3) * EC + e];
            const float wg0 = Wg[(c + 0) * EC + e];
            const float wg1 = Wg[(c + 1) * EC + e];
            const float wg2 = Wg[(c + 2) * EC + e];
            const float wg3 = Wg[(c + 3) * EC + e];
            #pragma unroll
            for (int w = 0; w < TILE; ++w) {
                float4 xv = *(const float4*)&xs[w0 + w][c];
                accp[w] = fmaf(xv.x, we0, accp[w]);
                accp[w] = fmaf(xv.y, we1, accp[w]);
                accp[w] = fmaf(xv.z, we2, accp[w]);
                accp[w] = fmaf(xv.w, we3, accp[w]);
                accg[w] = fmaf(xv.x, wg0, accg[w]);
                accg[w] = fmaf(xv.y, wg1, accg[w]);
                accg[w] = fmaf(xv.z, wg2, accg[w]);
                accg[w] = fmaf(xv.w, wg3, accg[w]);
            }
        }

        // ---- SSM scan (sequential along w) + sigmoid gate -> gated tile ----
        #pragma unroll
        for (int w = 0; w < TILE; ++w) {
            const float u = accp[w];
            float y = (float)SS * u * d;           // S * u * D broadcast term
            #pragma unroll
            for (int s = 0; s < SS; ++s) {
                st[s] = fmaf(st[s], Ar[s], u * Br[s]);   // st = st*A + u*B
                y = fmaf(st[s], Cr[s], y);               // y += st*C
            }
            const float g = 1.f / (1.f + expf(-accg[w]));
            gs[w][e] = g * y;
        }
        __syncthreads();

        // ---- output matmul: 16 pixels x 96 channels; thread -> (co, 8 pixels) ----
        {
            float acco[8];
            #pragma unroll
            for (int j = 0; j < 8; ++j) acco[j] = 0.f;

            for (int e4 = 0; e4 < EC / 4; ++e4) {
                const int ee = e4 * 4;
                const float wo0 = Wo[(ee + 0) * CHN + co];
                const float wo1 = Wo[(ee + 1) * CHN + co];
                const float wo2 = Wo[(ee + 2) * CHN + co];
                const float wo3 = Wo[(ee + 3) * CHN + co];
                #pragma unroll
                for (int j = 0; j < 8; ++j) {
                    float4 gv = *(const float4*)&gs[wgr * 8 + j][ee];
                    acco[j] = fmaf(gv.x, wo0, acco[j]);
                    acco[j] = fmaf(gv.y, wo1, acco[j]);
                    acco[j] = fmaf(gv.z, wo2, acco[j]);
                    acco[j] = fmaf(gv.w, wo3, acco[j]);
                }
            }
            #pragma unroll
            for (int j = 0; j < 8; ++j) {
                out[((size_t)row * WPIX + w0 + wgr * 8 + j) * CHN + co] = acco[j];
            }
        }
        __syncthreads();   // before gs is overwritten next tile
    }
}

extern "C" void kernel_launch(void* const* d_in, const int* in_sizes, int n_in,
                              void* d_out, int out_size, void* d_ws, size_t ws_size,
                              hipStream_t stream) {
    const float* in    = (const float*)d_in[0];
    const float* gamma = (const float*)d_in[1];
    const float* beta  = (const float*)d_in[2];
    const float* We    = (const float*)d_in[3];
    const float* Wg    = (const float*)d_in[4];
    const float* Ap    = (const float*)d_in[5];
    const float* Bp    = (const float*)d_in[6];
    const float* Cp    = (const float*)d_in[7];
    const float* Dp    = (const float*)d_in[8];
    const float* Wo    = (const float*)d_in[9];
    float* out = (float*)d_out;

    mamba_fused<<<dim3(8 * 128), dim3(NT), 0, stream>>>(
        in, gamma, beta, We, Wg, Ap, Bp, Cp, Dp, Wo, out);
}

// Round 2
// 438.333 us; speedup vs baseline: 1.2317x; 1.2317x over previous
//
#include <hip/hip_runtime.h>
#include <math.h>

#define CHN 96      // input/output channels
#define EC 192      // expanded channels
#define SS 16       // ssm state dim
#define WPIX 128    // sequence length (W axis)
#define TILE 16     // pixels per tile
#define NTILES (WPIX / TILE)
#define NT 192      // threads per block (= EC, 3 waves)

// launch_bounds(192, 4): 4 waves/EU min -> VGPR capped at 128 -> 16 waves/CU.
__global__ __launch_bounds__(NT, 4)
void mamba_fused(const float* __restrict__ in,
                 const float* __restrict__ gamma,
                 const float* __restrict__ beta,
                 const float* __restrict__ We,
                 const float* __restrict__ Wg,
                 const float* __restrict__ Ap,
                 const float* __restrict__ Bp,
                 const float* __restrict__ Cp,
                 const float* __restrict__ Dp,
                 const float* __restrict__ Wo,
                 float* __restrict__ out) {
    __shared__ float xs[TILE][CHN];    // normalized pixel tile, 6 KB
    __shared__ float gs[TILE][EC];     // gated tile, 12 KB
    __shared__ float gsm[CHN], bsm[CHN];

    const int t = threadIdx.x;
    const int row = blockIdx.x;                      // (b*128 + h)
    const float* inrow = in + (size_t)row * WPIX * CHN;

    // gamma/beta -> LDS once
    if (t < CHN) { gsm[t] = gamma[t]; bsm[t] = beta[t]; }

    // ---- persistent per-channel scan parameters (thread t owns channel e=t) ----
    const int e = t;
    float Ar[SS], Br[SS], Cr[SS], st[SS];
    const float d = Dp[e];
    #pragma unroll
    for (int s4 = 0; s4 < SS / 4; ++s4) {
        float4 a = *(const float4*)&Ap[e * SS + s4 * 4];
        float4 b = *(const float4*)&Bp[e * SS + s4 * 4];
        float4 c = *(const float4*)&Cp[e * SS + s4 * 4];
        Ar[s4*4+0]=a.x; Ar[s4*4+1]=a.y; Ar[s4*4+2]=a.z; Ar[s4*4+3]=a.w;
        Br[s4*4+0]=b.x; Br[s4*4+1]=b.y; Br[s4*4+2]=b.z; Br[s4*4+3]=b.w;
        Cr[s4*4+0]=c.x; Cr[s4*4+1]=c.y; Cr[s4*4+2]=c.z; Cr[s4*4+3]=c.w;
    }
    #pragma unroll
    for (int s = 0; s < SS; ++s) st[s] = 0.f;

    const int px = t >> 3;     // LN: pixel (0..15), threads 0..127
    const int ln = t & 7;      // LN: lane-in-pixel (0..7), 12 channels each
    const int co  = t % CHN;   // phase O: output channel
    const int wgr = t / CHN;   // phase O: pixel half (0/1)

    __syncthreads();           // gsm/bsm visible

    for (int tile = 0; tile < NTILES; ++tile) {
        const int w0 = tile * TILE;

        // ---- fused load + LayerNorm: global -> regs -> normalized LDS ----
        if (t < 128) {
            const float* pin = inrow + (size_t)(w0 + px) * CHN + ln * 12;
            float4 v0 = *(const float4*)(pin + 0);
            float4 v1 = *(const float4*)(pin + 4);
            float4 v2 = *(const float4*)(pin + 8);
            float sum = v0.x + v0.y + v0.z + v0.w
                      + v1.x + v1.y + v1.z + v1.w
                      + v2.x + v2.y + v2.z + v2.w;
            float sq = v0.x*v0.x + v0.y*v0.y + v0.z*v0.z + v0.w*v0.w
                     + v1.x*v1.x + v1.y*v1.y + v1.z*v1.z + v1.w*v1.w
                     + v2.x*v2.x + v2.y*v2.y + v2.z*v2.z + v2.w*v2.w;
            #pragma unroll
            for (int m = 1; m < 8; m <<= 1) {
                sum += __shfl_xor(sum, m);
                sq  += __shfl_xor(sq,  m);
            }
            const float mean = sum * (1.f / CHN);
            const float var  = sq * (1.f / CHN) - mean * mean;
            const float rstd = rsqrtf(var + 1e-3f);
            const int cb = ln * 12;
            float o[12] = {v0.x,v0.y,v0.z,v0.w, v1.x,v1.y,v1.z,v1.w, v2.x,v2.y,v2.z,v2.w};
            #pragma unroll
            for (int k = 0; k < 12; ++k)
                o[k] = (o[k] - mean) * rstd * gsm[cb + k] + bsm[cb + k];
            *(float4*)&xs[px][cb + 0] = make_float4(o[0], o[1], o[2],  o[3]);
            *(float4*)&xs[px][cb + 4] = make_float4(o[4], o[5], o[6],  o[7]);
            *(float4*)&xs[px][cb + 8] = make_float4(o[8], o[9], o[10], o[11]);
        }
        __syncthreads();

        // ---- expand + gate matmuls: acc over c, 16 pixels per weight load ----
        float accp[TILE], accg[TILE];
        #pragma unroll
        for (int w = 0; w < TILE; ++w) { accp[w] = 0.f; accg[w] = 0.f; }

        for (int c4 = 0; c4 < CHN / 4; ++c4) {
            const int c = c4 * 4;
            const float we0 = We[(c + 0) * EC + e];
            const float we1 = We[(c + 1) * EC + e];
            const float we2 = We[(c + 2) * EC + e];
            const float we3 = We[(c + 3) * EC + e];
            const float wg0 = Wg[(c + 0) * EC + e];
            const float wg1 = Wg[(c + 1) * EC + e];
            const float wg2 = Wg[(c + 2) * EC + e];
            const float wg3 = Wg[(c + 3) * EC + e];
            #pragma unroll
            for (int w = 0; w < TILE; ++w) {
                float4 xv = *(const float4*)&xs[w][c];    // broadcast
                accp[w] = fmaf(xv.x, we0, accp[w]);
                accp[w] = fmaf(xv.y, we1, accp[w]);
                accp[w] = fmaf(xv.z, we2, accp[w]);
                accp[w] = fmaf(xv.w, we3, accp[w]);
                accg[w] = fmaf(xv.x, wg0, accg[w]);
                accg[w] = fmaf(xv.y, wg1, accg[w]);
                accg[w] = fmaf(xv.z, wg2, accg[w]);
                accg[w] = fmaf(xv.w, wg3, accg[w]);
            }
        }

        // ---- SSM scan (sequential along w) + sigmoid gate -> gated tile ----
        #pragma unroll
        for (int w = 0; w < TILE; ++w) {
            const float u = accp[w];
            float y = (float)SS * u * d;               // S * u * D broadcast term
            #pragma unroll
            for (int s = 0; s < SS; ++s) {
                st[s] = fmaf(st[s], Ar[s], u * Br[s]); // st = st*A + u*B
                y = fmaf(st[s], Cr[s], y);             // y += st*C
            }
            const float g = 1.f / (1.f + expf(-accg[w]));
            gs[w][e] = g * y;
        }
        __syncthreads();

        // ---- output matmul: 16 px x 96 ch; thread -> (co, 8 pixels) ----
        {
            float acco[8];
            #pragma unroll
            for (int j = 0; j < 8; ++j) acco[j] = 0.f;

            for (int e4 = 0; e4 < EC / 4; ++e4) {
                const int ee = e4 * 4;
                const float wo0 = Wo[(ee + 0) * CHN + co];
                const float wo1 = Wo[(ee + 1) * CHN + co];
                const float wo2 = Wo[(ee + 2) * CHN + co];
                const float wo3 = Wo[(ee + 3) * CHN + co];
                #pragma unroll
                for (int j = 0; j < 8; ++j) {
                    float4 gv = *(const float4*)&gs[wgr * 8 + j][ee];  // broadcast
                    acco[j] = fmaf(gv.x, wo0, acco[j]);
                    acco[j] = fmaf(gv.y, wo1, acco[j]);
                    acco[j] = fmaf(gv.z, wo2, acco[j]);
                    acco[j] = fmaf(gv.w, wo3, acco[j]);
                }
            }
            #pragma unroll
            for (int j = 0; j < 8; ++j) {
                out[((size_t)row * WPIX + w0 + wgr * 8 + j) * CHN + co] = acco[j];
            }
        }
        __syncthreads();   // gs/xs reused next tile
    }
}

extern "C" void kernel_launch(void* const* d_in, const int* in_sizes, int n_in,
                              void* d_out, int out_size, void* d_ws, size_t ws_size,
                              hipStream_t stream) {
    const float* in    = (const float*)d_in[0];
    const float* gamma = (const float*)d_in[1];
    const float* beta  = (const float*)d_in[2];
    const float* We    = (const float*)d_in[3];
    const float* Wg    = (const float*)d_in[4];
    const float* Ap    = (const float*)d_in[5];
    const float* Bp    = (const float*)d_in[6];
    const float* Cp    = (const float*)d_in[7];
    const float* Dp    = (const float*)d_in[8];
    const float* Wo    = (const float*)d_in[9];
    float* out = (float*)d_out;

    mamba_fused<<<dim3(8 * 128), dim3(NT), 0, stream>>>(
        in, gamma, beta, We, Wg, Ap, Bp, Cp, Dp, Wo, out);
}

// Round 3
// 358.021 us; speedup vs baseline: 1.5080x; 1.2243x over previous
//
#include <hip/hip_runtime.h>
#include <math.h>

#define CHN 96      // input/output channels
#define EC 192      // expanded channels
#define SS 16       // ssm state dim
#define WPIX 128    // sequence length (W axis)
#define TILE 16     // pixels per tile
#define NTILES (WPIX / TILE)
#define NT 192      // threads per block (= EC, 3 waves)

// ---- prep1: We' = gamma (.) We, Wg' = gamma (.) Wg  (row c scaled) ----
__global__ void prep_scale(const float* __restrict__ We,
                           const float* __restrict__ Wg,
                           const float* __restrict__ gamma,
                           float* __restrict__ WeP,
                           float* __restrict__ WgP) {
    const int c = blockIdx.x;      // 0..95
    const int e = threadIdx.x;     // 0..191
    const float g = gamma[c];
    WeP[c * EC + e] = g * We[c * EC + e];
    WgP[c * EC + e] = g * Wg[c * EC + e];
}

// ---- prep2: column sums se = sum_c We'[c,e]; be = sum_c beta_c*We[c,e] ----
__global__ void prep_sums(const float* __restrict__ We,
                          const float* __restrict__ Wg,
                          const float* __restrict__ beta,
                          const float* __restrict__ WeP,
                          const float* __restrict__ WgP,
                          float* __restrict__ se, float* __restrict__ be,
                          float* __restrict__ sg, float* __restrict__ bg) {
    const int e = threadIdx.x;     // 0..191
    float s1 = 0.f, b1 = 0.f, s2 = 0.f, b2 = 0.f;
    for (int c = 0; c < CHN; ++c) {
        s1 += WeP[c * EC + e];
        s2 += WgP[c * EC + e];
        b1 += beta[c] * We[c * EC + e];
        b2 += beta[c] * Wg[c * EC + e];
    }
    se[e] = s1; be[e] = b1; sg[e] = s2; bg[e] = b2;
}

// expand-phase weight prefetch: 8 scalar loads (4 We' + 4 Wg') for quad c4
#define LOADW(W, c4) {                                         \
    W##0 = wep[((c4) * 4 + 0) * EC]; W##1 = wep[((c4) * 4 + 1) * EC]; \
    W##2 = wep[((c4) * 4 + 2) * EC]; W##3 = wep[((c4) * 4 + 3) * EC]; \
    W##4 = wgp[((c4) * 4 + 0) * EC]; W##5 = wgp[((c4) * 4 + 1) * EC]; \
    W##6 = wgp[((c4) * 4 + 2) * EC]; W##7 = wgp[((c4) * 4 + 3) * EC]; }

#define FMAB(W, c4) {                                          \
    _Pragma("unroll")                                          \
    for (int w = 0; w < TILE; ++w) {                           \
        float4 xv = *(const float4*)(xtile + w * CHN + (c4) * 4); \
        accp[w] = fmaf(xv.x, W##0, accp[w]);                   \
        accp[w] = fmaf(xv.y, W##1, accp[w]);                   \
        accp[w] = fmaf(xv.z, W##2, accp[w]);                   \
        accp[w] = fmaf(xv.w, W##3, accp[w]);                   \
        accg[w] = fmaf(xv.x, W##4, accg[w]);                   \
        accg[w] = fmaf(xv.y, W##5, accg[w]);                   \
        accg[w] = fmaf(xv.z, W##6, accg[w]);                   \
        accg[w] = fmaf(xv.w, W##7, accg[w]); } }

// phase-O weight prefetch: 16 Wo values for e-chunk ch (16 e's)
#define LOADO(W, ch) {                                         \
    _Pragma("unroll")                                          \
    for (int k = 0; k < 16; ++k) W[k] = Wo[((ch) * 16 + k) * CHN + co]; }

#define FMAO(W, ch) {                                          \
    _Pragma("unroll")                                          \
    for (int j = 0; j < 8; ++j) {                              \
        const float* gp_ = &gs[wgr * 8 + j][(ch) * 16];        \
        _Pragma("unroll")                                      \
        for (int k4 = 0; k4 < 4; ++k4) {                       \
            float4 gv = *(const float4*)(gp_ + k4 * 4);        \
            acco[j] = fmaf(gv.x, W[k4 * 4 + 0], acco[j]);      \
            acco[j] = fmaf(gv.y, W[k4 * 4 + 1], acco[j]);      \
            acco[j] = fmaf(gv.z, W[k4 * 4 + 2], acco[j]);      \
            acco[j] = fmaf(gv.w, W[k4 * 4 + 3], acco[j]); } } }

__global__ __launch_bounds__(NT, 3)
void mamba_fused(const float* __restrict__ in,
                 const float* __restrict__ WeP,
                 const float* __restrict__ WgP,
                 const float* __restrict__ sev,
                 const float* __restrict__ bev,
                 const float* __restrict__ sgv,
                 const float* __restrict__ bgv,
                 const float* __restrict__ Ap,
                 const float* __restrict__ Bp,
                 const float* __restrict__ Cp,
                 const float* __restrict__ Dp,
                 const float* __restrict__ Wo,
                 float* __restrict__ out) {
    __shared__ float gs[TILE][EC];       // gated tile, 12.3 KB
    __shared__ float2 stats[TILE];       // (rstd, mu*rstd) per pixel

    const int t = threadIdx.x;
    const int row = blockIdx.x;                      // (b*128 + h)
    const float* inrow = in + (size_t)row * WPIX * CHN;

    // ---- per-channel persistent params (thread t owns channel e=t) ----
    const int e = t;
    const float* wep = WeP + e;
    const float* wgp = WgP + e;
    float Ar[SS], Br[SS], Cr[SS], st[SS];
    const float dd = Dp[e];
    const float se_r = sev[e], be_r = bev[e], sg_r = sgv[e], bg_r = bgv[e];
    #pragma unroll
    for (int s4 = 0; s4 < SS / 4; ++s4) {
        float4 a = *(const float4*)&Ap[e * SS + s4 * 4];
        float4 b = *(const float4*)&Bp[e * SS + s4 * 4];
        float4 c = *(const float4*)&Cp[e * SS + s4 * 4];
        Ar[s4*4+0]=a.x; Ar[s4*4+1]=a.y; Ar[s4*4+2]=a.z; Ar[s4*4+3]=a.w;
        Br[s4*4+0]=b.x; Br[s4*4+1]=b.y; Br[s4*4+2]=b.z; Br[s4*4+3]=b.w;
        Cr[s4*4+0]=c.x; Cr[s4*4+1]=c.y; Cr[s4*4+2]=c.z; Cr[s4*4+3]=c.w;
    }
    #pragma unroll
    for (int s = 0; s < SS; ++s) st[s] = 0.f;

    const int px  = t >> 3;    // stats: pixel (0..15), threads 0..127
    const int ln  = t & 7;     // stats: lane-in-pixel (0..7)
    const int co  = t % CHN;   // phase O: output channel
    const int wgr = t / CHN;   // phase O: pixel half (0/1)

    for (int tile = 0; tile < NTILES; ++tile) {
        const int w0 = tile * TILE;
        const float* xtile = inrow + (size_t)w0 * CHN;

        // ---- per-pixel LN stats only (normalize folded into weights) ----
        if (t < 128) {
            const float* pin = xtile + (size_t)px * CHN + ln * 12;
            float4 v0 = *(const float4*)(pin + 0);
            float4 v1 = *(const float4*)(pin + 4);
            float4 v2 = *(const float4*)(pin + 8);
            float sum = v0.x + v0.y + v0.z + v0.w
                      + v1.x + v1.y + v1.z + v1.w
                      + v2.x + v2.y + v2.z + v2.w;
            float sq = v0.x*v0.x + v0.y*v0.y + v0.z*v0.z + v0.w*v0.w
                     + v1.x*v1.x + v1.y*v1.y + v1.z*v1.z + v1.w*v1.w
                     + v2.x*v2.x + v2.y*v2.y + v2.z*v2.z + v2.w*v2.w;
            #pragma unroll
            for (int m = 1; m < 8; m <<= 1) {
                sum += __shfl_xor(sum, m);
                sq  += __shfl_xor(sq,  m);
            }
            const float mean = sum * (1.f / CHN);
            const float var  = sq * (1.f / CHN) - mean * mean;
            const float rstd = rsqrtf(var + 1e-3f);
            if (ln == 0) stats[px] = make_float2(rstd, mean * rstd);
        }
        __syncthreads();

        // ---- expand + gate on RAW x (broadcast L1 loads), pipelined weights ----
        float accp[TILE], accg[TILE];
        #pragma unroll
        for (int w = 0; w < TILE; ++w) { accp[w] = 0.f; accg[w] = 0.f; }

        {
            float wA0, wA1, wA2, wA3, wA4, wA5, wA6, wA7;
            float wB0, wB1, wB2, wB3, wB4, wB5, wB6, wB7;
            LOADW(wA, 0);
            for (int c4 = 0; c4 < 24; c4 += 2) {
                LOADW(wB, c4 + 1);
                FMAB(wA, c4);
                const int nx = (c4 + 2 < 24) ? c4 + 2 : 0;
                LOADW(wA, nx);
                FMAB(wB, c4 + 1);
            }
        }

        // ---- LN fixup + SSM scan + sigmoid gate -> gated tile ----
        #pragma unroll
        for (int w = 0; w < TILE; ++w) {
            const float2 sp = stats[w];              // broadcast b64
            const float u  = fmaf(accp[w], sp.x, fmaf(-sp.y, se_r, be_r));
            const float gp = fmaf(accg[w], sp.x, fmaf(-sp.y, sg_r, bg_r));
            float y = (float)SS * u * dd;            // S*u*D broadcast term
            #pragma unroll
            for (int s = 0; s < SS; ++s) {
                st[s] = fmaf(st[s], Ar[s], u * Br[s]);
                y = fmaf(st[s], Cr[s], y);
            }
            const float g = 1.f / (1.f + __expf(-gp));
            gs[w][e] = g * y;
        }
        __syncthreads();

        // ---- output matmul, pipelined Wo in 16-e chunks (12 chunks) ----
        {
            float acco[8];
            #pragma unroll
            for (int j = 0; j < 8; ++j) acco[j] = 0.f;

            float WA[16], WB[16];
            LOADO(WA, 0);
            for (int ch = 0; ch < 12; ch += 2) {
                LOADO(WB, ch + 1);
                FMAO(WA, ch);
                const int nx = (ch + 2 < 12) ? ch + 2 : 0;
                LOADO(WA, nx);
                FMAO(WB, ch + 1);
            }

            #pragma unroll
            for (int j = 0; j < 8; ++j) {
                out[((size_t)row * WPIX + w0 + wgr * 8 + j) * CHN + co] = acco[j];
            }
        }
        // NOTE: no barrier here. gs writes for tile t+1 happen after the
        // stats-phase barrier of t+1, which every wave only passes after
        // finishing phase O of tile t.
    }
}

extern "C" void kernel_launch(void* const* d_in, const int* in_sizes, int n_in,
                              void* d_out, int out_size, void* d_ws, size_t ws_size,
                              hipStream_t stream) {
    const float* in    = (const float*)d_in[0];
    const float* gamma = (const float*)d_in[1];
    const float* beta  = (const float*)d_in[2];
    const float* We    = (const float*)d_in[3];
    const float* Wg    = (const float*)d_in[4];
    const float* Ap    = (const float*)d_in[5];
    const float* Bp    = (const float*)d_in[6];
    const float* Cp    = (const float*)d_in[7];
    const float* Dp    = (const float*)d_in[8];
    const float* Wo    = (const float*)d_in[9];
    float* out = (float*)d_out;

    float* wsf = (float*)d_ws;
    float* WeP = wsf;                 // 96*192
    float* WgP = wsf + 18432;         // 96*192
    float* se  = wsf + 36864;         // 192
    float* be  = wsf + 37056;
    float* sg  = wsf + 37248;
    float* bg  = wsf + 37440;         // end 37632 floats = 147 KB

    prep_scale<<<dim3(CHN), dim3(EC), 0, stream>>>(We, Wg, gamma, WeP, WgP);
    prep_sums<<<dim3(1), dim3(EC), 0, stream>>>(We, Wg, beta, WeP, WgP, se, be, sg, bg);
    mamba_fused<<<dim3(8 * 128), dim3(NT), 0, stream>>>(
        in, WeP, WgP, se, be, sg, bg, Ap, Bp, Cp, Dp, Wo, out);
}